// Round 8
// baseline (582.596 us; speedup 1.0000x reference)
//
#include <hip/hip_runtime.h>

// EUNN: 256 layers; each layer = rotation on even pairs (2i,2i+1), then
// rotation on odd pairs (2i+1,2i+2 mod H).
// Pair math: y0 = e^{i*phi} (ct*u - st*v); y1 = st*u + ct*v.
//
// Journal: R1 423us (RPW=4, grid 256, occupancy-limited). R2/R6: register
// coef double-buffer => allocator collapse (~60 VGPR, AGPR churn) => 546-1080us.
// R3: (256,4) VGPR squeeze => 526us. R4: RPW=2, grid 512, (256,2) => 370us,
// VALUBusy 64%, VGPR 76. R5: LDS staging + per-layer barrier => 431us.
// R7: float2 hoping for SLP packed-fp32 => no codegen change (373us).
// R8 (this): explicit inline-asm v_pk_mul/fma_f32 with op_sel broadcast/swap
// => 6 packed VALU per pair instead of 12 scalar.

#define H_DIM 1024
#define C2 256
#define RPW 2   // batch rows per wave

typedef float v2f __attribute__((ext_vector_type(2)));
typedef float v4f __attribute__((ext_vector_type(4)));

// coef layout: [c][j][lane] as float4 (ct, st, cp, sp); j in [0,16):
//   j=0..7  : phase A pair (local 2j, 2j+1) of lane
//   j=8..14 : phase B internal pair (local 2j-15, 2j-14)
//   j=15    : phase B boundary pair (lane elem15, next lane's elem0)
// flat float4 index: (c*16 + j)*64 + lane,  16 KB per layer, 4 MB total.

__global__ __launch_bounds__(256) void eunn_coef_kernel(
    const float* __restrict__ phi0, const float* __restrict__ theta0,
    const float* __restrict__ phi1, const float* __restrict__ theta1,
    float4* __restrict__ coef) {
    int t = blockIdx.x * 256 + threadIdx.x;   // [0, 262144)
    int c = t & 255;                          // layer in low bits -> coalesced reads
    int ip = t >> 8;                          // [0,1024)
    int i = ip >> 1;                          // pair index [0,512)
    int p = ip & 1;                           // phase
    const float* phi   = p ? phi1   : phi0;
    const float* theta = p ? theta1 : theta0;
    float ph = phi[i * C2 + c];
    float th = theta[i * C2 + c];
    float sp, cp, st, ct;
    __sincosf(ph, &sp, &cp);
    __sincosf(th, &st, &ct);
    int j = (i & 7) + 8 * p;                  // j slot: A pairs 0..7, B pairs 8..15
    int l = i >> 3;
    coef[((c * 16) + j) * 64 + l] = make_float4(ct, st, cp, sp);
}

// Packed-fp32 complex pair rotation: u,w hold (re,im) in a 64-bit VGPR pair;
// qts = (ct,st), qph = (cp,sp). op_sel broadcasts/swaps halves in-instruction.
//   A  = ct*u - st*w                (2 pk ops)
//   B  = st*u + ct*w                (2 pk ops)
//   u' = e^{i phi} * A              (2 pk ops; swap+neg via op_sel/neg_lo)
//   w' = B
__device__ __forceinline__ void rot_pair_pk(v2f qts, v2f qph, v2f& u, v2f& w) {
    v2f A, B;
    // A = (ct*u.re, ct*u.im)
    asm("v_pk_mul_f32 %0, %1, %2 op_sel:[0,0] op_sel_hi:[0,1]"
        : "=v"(A) : "v"(qts), "v"(u));
    // A += (-st)*w  (both halves)
    asm("v_pk_fma_f32 %0, %1, %2, %0 op_sel:[1,0,0] op_sel_hi:[1,1,1] neg_lo:[1,0,0] neg_hi:[1,0,0]"
        : "+v"(A) : "v"(qts), "v"(w));
    // B = (st*u.re, st*u.im)
    asm("v_pk_mul_f32 %0, %1, %2 op_sel:[1,0] op_sel_hi:[1,1]"
        : "=v"(B) : "v"(qts), "v"(u));
    // B += ct*w  (both halves)
    asm("v_pk_fma_f32 %0, %1, %2, %0 op_sel:[0,0,0] op_sel_hi:[0,1,1]"
        : "+v"(B) : "v"(qts), "v"(w));
    // T = (cp*A.re, cp*A.im)
    v2f T;
    asm("v_pk_mul_f32 %0, %1, %2 op_sel:[0,0] op_sel_hi:[0,1]"
        : "=v"(T) : "v"(qph), "v"(A));
    // u = (T.re - sp*A.im, T.im + sp*A.re): sp bcast, A swapped, neg on lo
    asm("v_pk_fma_f32 %0, %2, %3, %0 op_sel:[1,1,0] op_sel_hi:[1,0,1] neg_lo:[1,0,0] neg_hi:[0,0,0]"
        : "=v"(u), "+v"(T) : "v"(qph), "v"(A), "0"(T));
    u = T;
    w = B;
}

// Simpler correct form of the last op (keep compiler-friendly tie):
__device__ __forceinline__ void rot_pair_pk2(v2f qts, v2f qph, v2f& u, v2f& w) {
    v2f A, B, T;
    asm("v_pk_mul_f32 %0, %1, %2 op_sel:[0,0] op_sel_hi:[0,1]"
        : "=v"(A) : "v"(qts), "v"(u));
    asm("v_pk_fma_f32 %0, %1, %2, %0 op_sel:[1,0,0] op_sel_hi:[1,1,1] neg_lo:[1,0,0] neg_hi:[1,0,0]"
        : "+v"(A) : "v"(qts), "v"(w));
    asm("v_pk_mul_f32 %0, %1, %2 op_sel:[1,0] op_sel_hi:[1,1]"
        : "=v"(B) : "v"(qts), "v"(u));
    asm("v_pk_fma_f32 %0, %1, %2, %0 op_sel:[0,0,0] op_sel_hi:[0,1,1]"
        : "+v"(B) : "v"(qts), "v"(w));
    asm("v_pk_mul_f32 %0, %1, %2 op_sel:[0,0] op_sel_hi:[0,1]"
        : "=v"(T) : "v"(qph), "v"(A));
    asm("v_pk_fma_f32 %0, %1, %2, %0 op_sel:[1,1,0] op_sel_hi:[1,0,1] neg_lo:[1,0,0] neg_hi:[0,0,0]"
        : "+v"(T) : "v"(qph), "v"(A));
    u = T;
    w = B;
}

// NOTE (R3): keep min-waves at 2. NOTE (R2/R6): no register coef double-buffer.
__global__ __launch_bounds__(256, 2) void eunn_main_kernel(
    const float* __restrict__ x,
    const v4f* __restrict__ coef,
    float* __restrict__ out) {
    const int lane = threadIdx.x & 63;
    const int wave = threadIdx.x >> 6;
    const int row0 = (blockIdx.x * 4 + wave) * RPW;

    // lane owns complex elements [16*lane, 16*lane+16) of each of its RPW rows
    v2f v[RPW][16];

#pragma unroll
    for (int r = 0; r < RPW; ++r) {
        const v4f* src = (const v4f*)(x + (size_t)(row0 + r) * (H_DIM * 2)) + lane * 8;
#pragma unroll
        for (int m = 0; m < 8; ++m) {
            v4f f = src[m];
            v[r][2 * m]     = __builtin_shufflevector(f, f, 0, 1);
            v[r][2 * m + 1] = __builtin_shufflevector(f, f, 2, 3);
        }
    }

    const v4f* cl = coef + lane;   // lane-offset base, strength-reduced in loop

#pragma unroll 1
    for (int c = 0; c < C2; ++c) {
        const v4f* ca = cl + (size_t)c * 1024;

        // boundary coef for phase B, loaded up front; prev-lane copy via shuffle
        v4f qq = ca[15 * 64];
        float qpx = __shfl(qq.x, (lane + 63) & 63);   // prev lane's ct'
        float qpy = __shfl(qq.y, (lane + 63) & 63);   // prev lane's st'

        // --- phase A, boundary-adjacent pairs first (j=0 and j=7) so the
        // cross-lane shuffles can issue early and hide under the FMA work.
        {
            v4f q0 = ca[0 * 64];
            v4f q7 = ca[7 * 64];
            v2f q0ts = __builtin_shufflevector(q0, q0, 0, 1);
            v2f q0ph = __builtin_shufflevector(q0, q0, 2, 3);
            v2f q7ts = __builtin_shufflevector(q7, q7, 0, 1);
            v2f q7ph = __builtin_shufflevector(q7, q7, 2, 3);
#pragma unroll
            for (int r = 0; r < RPW; ++r) {
                rot_pair_pk2(q0ts, q0ph, v[r][0],  v[r][1]);
                rot_pair_pk2(q7ts, q7ph, v[r][14], v[r][15]);
            }
        }
        // post-phase-A elem0 / elem15 feed the phase-B boundary pair
        float nbr[RPW], nbi[RPW], pbr[RPW], pbi[RPW];
#pragma unroll
        for (int r = 0; r < RPW; ++r) {
            nbr[r] = __shfl(v[r][0].x,  (lane + 1)  & 63);   // next lane's elem0
            nbi[r] = __shfl(v[r][0].y,  (lane + 1)  & 63);
            pbr[r] = __shfl(v[r][15].x, (lane + 63) & 63);   // prev lane's elem15
            pbi[r] = __shfl(v[r][15].y, (lane + 63) & 63);
        }

        // --- phase A remaining pairs j=1..6
#pragma unroll
        for (int j = 1; j < 7; ++j) {
            v4f q = ca[j * 64];
            v2f qts = __builtin_shufflevector(q, q, 0, 1);
            v2f qph = __builtin_shufflevector(q, q, 2, 3);
#pragma unroll
            for (int r = 0; r < RPW; ++r) {
                rot_pair_pk2(qts, qph, v[r][2 * j], v[r][2 * j + 1]);
            }
        }

        // --- phase B internal pairs (local 2j+1, 2j+2), j=0..6
#pragma unroll
        for (int j = 0; j < 7; ++j) {
            v4f q = ca[(8 + j) * 64];
            v2f qts = __builtin_shufflevector(q, q, 0, 1);
            v2f qph = __builtin_shufflevector(q, q, 2, 3);
#pragma unroll
            for (int r = 0; r < RPW; ++r) {
                rot_pair_pk2(qts, qph, v[r][2 * j + 1], v[r][2 * j + 2]);
            }
        }

        // --- phase B boundary pair (my elem15, next lane's elem0): both
        // sides computed locally from the pre-issued shuffles. Scalar math
        // (verified since R3); small fraction of total VALU.
#pragma unroll
        for (int r = 0; r < RPW; ++r) {
            // new elem15 = e^{i phi}(ct*e15 - st*next_e0)
            float ar = fmaf(-qq.y, nbr[r], qq.x * v[r][15].x);
            float ai = fmaf(-qq.y, nbi[r], qq.x * v[r][15].y);
            v[r][15].x = fmaf(-qq.w, ai, qq.z * ar);
            v[r][15].y = fmaf( qq.w, ar, qq.z * ai);
            // new elem0 = st'*prev_e15 + ct'*e0  (lane-1's pair, second row)
            float b0x = fmaf(qpx, v[r][0].x, qpy * pbr[r]);
            float b0y = fmaf(qpx, v[r][0].y, qpy * pbi[r]);
            v[r][0].x = b0x; v[r][0].y = b0y;
        }
    }

#pragma unroll
    for (int r = 0; r < RPW; ++r) {
        v4f* dst = (v4f*)(out + (size_t)(row0 + r) * (H_DIM * 2)) + lane * 8;
#pragma unroll
        for (int m = 0; m < 8; ++m) {
            dst[m] = __builtin_shufflevector(v[r][2 * m], v[r][2 * m + 1], 0, 1, 2, 3);
        }
    }
}

extern "C" void kernel_launch(void* const* d_in, const int* in_sizes, int n_in,
                              void* d_out, int out_size, void* d_ws, size_t ws_size,
                              hipStream_t stream) {
    const float* x      = (const float*)d_in[0];
    const float* phi0   = (const float*)d_in[1];
    const float* theta0 = (const float*)d_in[2];
    const float* phi1   = (const float*)d_in[3];
    const float* theta1 = (const float*)d_in[4];
    float* out = (float*)d_out;
    float4* coef = (float4*)d_ws;   // 256 layers * 16 * 64 float4 = 4 MB

    // coefficients: 256 layers * 2 phases * 512 pairs = 262144 threads
    hipLaunchKernelGGL(eunn_coef_kernel, dim3(1024), dim3(256), 0, stream,
                       phi0, theta0, phi1, theta1, coef);

    // main: 4096 rows / (4 waves/block * RPW rows/wave) = 512 blocks
    hipLaunchKernelGGL(eunn_main_kernel, dim3(512), dim3(256), 0, stream,
                       x, (const v4f*)coef, out);
}